// Round 11
// baseline (91.797 us; speedup 1.0000x reference)
//
#include <hip/hip_runtime.h>

#define SB 32      // batch
#define SS 2048    // sequence
#define SH 2       // heads
#define SD 4       // head dim
#define SE 8       // embed

#define KCHUNKS 8
#define CHK (SS / KCHUNKS)    // 256 keys per chunk
#define RROWS 8               // q rows per thread; 256*8 = 2048 = SS (QTILES=1)

#define LOG2E 1.44269504f

typedef float f32x2 __attribute__((ext_vector_type(2)));
static __device__ __forceinline__ f32x2 fma2(f32x2 a, f32x2 b, f32x2 c) {
    return __builtin_elementwise_fma(a, b, c);
}

// Raw v_exp_f32 (1 trans instr). Without -ffast-math, libm exp2f lowers to
// the OCML denormal-safe path (~5 instr). Args are in [-100, 0].
static __device__ __forceinline__ float fast_exp2(float x) {
#if __has_builtin(__builtin_amdgcn_exp2f)
    return __builtin_amdgcn_exp2f(x);
#else
    return exp2f(x);
#endif
}

// ---------------------------------------------------------------------------
// Kernel 1: moving averages + QKV projection (q pre-scaled by log2e/sqrt(D)),
// K/V stored interleaved (one 32B record per key), and per-(b,h) global max
// of |q|^2 / |k|^2 via LDS reduce + atomicMax (values >= 0 so int-compare
// atomicMax is order-preserving).
// ---------------------------------------------------------------------------
__global__ __launch_bounds__(256) void k_ma_qkv(
    const float* __restrict__ x,      // [B,S]
    const float* __restrict__ Wq,     // [4,4] row-major W[e*4+d]
    const float* __restrict__ Wk,
    const float* __restrict__ Wv,
    float4* __restrict__ qws,         // [B*H*S]
    float4* __restrict__ kvws,        // [B*H*S*2] interleaved K,V
    float4* __restrict__ mmws,        // [B*S*2]
    float* __restrict__ Mq2,          // [B*H] (zero-initialized)
    float* __restrict__ Mk2)          // [B*H]
{
    __shared__ float xs[272];
    __shared__ float4 red4[256];

    const int tile = blockIdx.x % (SS / 256);
    const int b    = blockIdx.x / (SS / 256);
    const int s0   = tile * 256;
    const float* xrow = x + b * SS;

    for (int i = threadIdx.x; i < 272; i += 256) {
        int idx = s0 - 8 + i;
        idx = min(max(idx, 0), SS - 1);
        xs[i] = xrow[idx];
    }
    __syncthreads();

    const int t = threadIdx.x;
    const int s = s0 + t;

    float mmv[8];
    float c = xs[8 + t];
    #pragma unroll
    for (int h = 1; h <= 8; ++h) {
        c += xs[8 + t - h] + xs[8 + t + h];
        mmv[h - 1] = c * (1.0f / (float)(2 * h + 1));
    }

    mmws[(b * SS + s) * 2 + 0] = make_float4(mmv[0], mmv[1], mmv[2], mmv[3]);
    mmws[(b * SS + s) * 2 + 1] = make_float4(mmv[4], mmv[5], mmv[6], mmv[7]);

    const float qscale = 0.5f * LOG2E;  // 1/sqrt(D) * log2(e)
    float q2h[SH], k2h[SH];
    #pragma unroll
    for (int h = 0; h < SH; ++h) {
        const float t0 = mmv[h * 4 + 0];
        const float t1 = mmv[h * 4 + 1];
        const float t2 = mmv[h * 4 + 2];
        const float t3 = mmv[h * 4 + 3];
        float q[4], k[4], v[4];
        #pragma unroll
        for (int e = 0; e < 4; ++e) {
            q[e] = (t0 * Wq[e * 4 + 0] + t1 * Wq[e * 4 + 1] +
                    t2 * Wq[e * 4 + 2] + t3 * Wq[e * 4 + 3]) * qscale;
            k[e] =  t0 * Wk[e * 4 + 0] + t1 * Wk[e * 4 + 1] +
                    t2 * Wk[e * 4 + 2] + t3 * Wk[e * 4 + 3];
            v[e] =  t0 * Wv[e * 4 + 0] + t1 * Wv[e * 4 + 1] +
                    t2 * Wv[e * 4 + 2] + t3 * Wv[e * 4 + 3];
        }
        const int idx = (b * SH + h) * SS + s;
        qws[idx]          = make_float4(q[0], q[1], q[2], q[3]);
        kvws[idx * 2 + 0] = make_float4(k[0], k[1], k[2], k[3]);
        kvws[idx * 2 + 1] = make_float4(v[0], v[1], v[2], v[3]);
        q2h[h] = q[0]*q[0] + q[1]*q[1] + q[2]*q[2] + q[3]*q[3];
        k2h[h] = k[0]*k[0] + k[1]*k[1] + k[2]*k[2] + k[3]*k[3];
    }

    red4[t] = make_float4(q2h[0], k2h[0], q2h[1], k2h[1]);
    __syncthreads();
    #pragma unroll
    for (int sft = 128; sft > 0; sft >>= 1) {
        if (t < sft) {
            float4 a = red4[t], bb = red4[t + sft];
            red4[t] = make_float4(fmaxf(a.x, bb.x), fmaxf(a.y, bb.y),
                                  fmaxf(a.z, bb.z), fmaxf(a.w, bb.w));
        }
        __syncthreads();
    }
    if (t == 0) {
        const float4 r = red4[0];
        atomicMax((int*)&Mq2[b * SH + 0], __float_as_int(r.x));
        atomicMax((int*)&Mk2[b * SH + 0], __float_as_int(r.y));
        atomicMax((int*)&Mq2[b * SH + 1], __float_as_int(r.z));
        atomicMax((int*)&Mk2[b * SH + 1], __float_as_int(r.w));
    }
}

// ---------------------------------------------------------------------------
// Kernel 2: attention, single pass, RROWS=8 streams/thread (256 threads * 8
// rows = all 2048 q rows per block — QTILES=1, no tiling arithmetic).
// Halves per-CU ds_read traffic vs RROWS=4 (LDS pipe was ~50% of duration
// in R10's budget). K/V chunk (8 KB) in LDS; j wave-uniform -> broadcast.
// Shift bound m = sqrt(Mq2*Mk2) per (b,h) seeds the dot; base-2; raw exp2.
// Grid = B*H * KCHUNKS = 512 blocks -> 2 blocks/CU, 8 waves/CU; 8-way ILP
// per thread carries the latency hiding (R4-vs-R7 evidence).
// ---------------------------------------------------------------------------
__global__ __launch_bounds__(256, 2) void k_attn(
    const float4* __restrict__ qws,
    const float4* __restrict__ kvws,
    const float* __restrict__ Mq2,
    const float* __restrict__ Mk2,
    float* __restrict__ pl,      // [KCHUNKS * B*H*S]  partial sums l
    float4* __restrict__ pacc)   // [KCHUNKS * B*H*S]
{
    __shared__ float4 KVsh[2 * CHK];   // 8 KB interleaved {K,V} records

    const int kc = blockIdx.x % KCHUNKS;
    const int bh = blockIdx.x / KCHUNKS;

    const int t = threadIdx.x;

    const float4* __restrict__ KVg = kvws + (bh * SS + kc * CHK) * 2;
    #pragma unroll
    for (int i = 0; i < 2 * CHK / 256; ++i)
        KVsh[i * 256 + t] = KVg[i * 256 + t];

    const float mq = -sqrtf(Mq2[bh] * Mk2[bh]);   // -m, log2 units

    f32x2 qlo[RROWS], qhi[RROWS];
    #pragma unroll
    for (int i = 0; i < RROWS; ++i) {
        const float4 q = qws[bh * SS + i * 256 + t];
        qlo[i] = f32x2{q.x, q.y};
        qhi[i] = f32x2{q.z, q.w};
    }

    float l[RROWS];
    f32x2 acclo[RROWS], acchi[RROWS];
    #pragma unroll
    for (int i = 0; i < RROWS; ++i) {
        l[i] = 0.f;
        acclo[i] = f32x2{0.f, 0.f};
        acchi[i] = f32x2{0.f, 0.f};
    }

    __syncthreads();

    #pragma unroll 2
    for (int j = 0; j < CHK; ++j) {
        const float4 k4 = KVsh[2 * j];       // uniform addr -> broadcast
        const float4 v4 = KVsh[2 * j + 1];
        const f32x2 klo = {k4.x, k4.y}, khi = {k4.z, k4.w};
        const f32x2 vlo = {v4.x, v4.y}, vhi = {v4.z, v4.w};
        #pragma unroll
        for (int i = 0; i < RROWS; ++i) {
            f32x2 d = fma2(qlo[i], klo, f32x2{mq, 0.f});
            d = fma2(qhi[i], khi, d);
            const float p = fast_exp2(d.x + d.y);   // arg = q.k - m, in [-100,0]
            l[i] += p;
            const f32x2 pp = {p, p};
            acclo[i] = fma2(pp, vlo, acclo[i]);
            acchi[i] = fma2(pp, vhi, acchi[i]);
        }
    }

    #pragma unroll
    for (int i = 0; i < RROWS; ++i) {
        const int idx = (kc * SB * SH + bh) * SS + i * 256 + t;
        pl[idx]   = l[i];
        pacc[idx] = make_float4(acclo[i].x, acclo[i].y, acchi[i].x, acchi[i].y);
    }
}

// ---------------------------------------------------------------------------
// Kernel 3: epilogue. Shift m identical across k-chunks -> plain-sum merge.
// Then o @ Wo^T + bo, channel softmax, trend, seasonal.
// ---------------------------------------------------------------------------
__global__ __launch_bounds__(256) void k_epilogue(
    const float* __restrict__ x,      // [B,S]
    const float* __restrict__ Wo,     // [8,8]
    const float* __restrict__ bo,     // [8]
    const float* __restrict__ pl,
    const float4* __restrict__ pacc,
    const float4* __restrict__ mmws,
    float* __restrict__ out)          // seasonal [B*S] then trend [B*S]
{
    const int pos = blockIdx.x * 256 + threadIdx.x;  // = b*S + s
    const int b = pos / SS;
    const int s = pos % SS;

    float ov[8];
    #pragma unroll
    for (int h = 0; h < SH; ++h) {
        const int bh = b * SH + h;
        float lsum = 0.f, ax = 0.f, ay = 0.f, az = 0.f, aw = 0.f;
        #pragma unroll
        for (int kc = 0; kc < KCHUNKS; ++kc) {
            const int idx = (kc * SB * SH + bh) * SS + s;
            const float4 pa = pacc[idx];
            lsum += pl[idx];
            ax += pa.x; ay += pa.y; az += pa.z; aw += pa.w;
        }
        const float inv = 1.0f / lsum;
        ov[h * 4 + 0] = ax * inv;
        ov[h * 4 + 1] = ay * inv;
        ov[h * 4 + 2] = az * inv;
        ov[h * 4 + 3] = aw * inv;
    }

    float g[8];
    float m = -1e30f;
    #pragma unroll
    for (int e = 0; e < 8; ++e) {
        float acc = bo[e];
        #pragma unroll
        for (int f = 0; f < 8; ++f) acc += ov[f] * Wo[e * 8 + f];
        g[e] = acc;
        m = fmaxf(m, acc);
    }
    float l = 0.0f;
    #pragma unroll
    for (int e = 0; e < 8; ++e) { g[e] = __expf(g[e] - m); l += g[e]; }
    const float inv = 1.0f / l;

    const float4 mm0 = mmws[pos * 2 + 0];
    const float4 mm1 = mmws[pos * 2 + 1];
    const float mv[8] = {mm0.x, mm0.y, mm0.z, mm0.w, mm1.x, mm1.y, mm1.z, mm1.w};

    float trend = 0.0f;
    #pragma unroll
    for (int e = 0; e < 8; ++e) trend += g[e] * inv * mv[e];

    out[pos]           = x[pos] - trend;   // seasonal
    out[SB * SS + pos] = trend;            // trend
}

extern "C" void kernel_launch(void* const* d_in, const int* in_sizes, int n_in,
                              void* d_out, int out_size, void* d_ws, size_t ws_size,
                              hipStream_t stream) {
    const float* x  = (const float*)d_in[0];
    const float* Wq = (const float*)d_in[1];
    const float* Wk = (const float*)d_in[2];
    const float* Wv = (const float*)d_in[3];
    const float* Wo = (const float*)d_in[4];
    const float* bo = (const float*)d_in[5];

    float*  Mq2  = (float*)d_ws;                              // 64 floats
    float*  Mk2  = Mq2 + SB * SH;                             // 64 floats (512 B total)
    float4* qws  = (float4*)((char*)d_ws + 512);              // 2 MB
    float4* kvws = qws + SB * SH * SS;                        // 4 MB (interleaved K,V)
    float4* mmws = kvws + 2 * SB * SH * SS;                   // 2 MB
    float4* pacc = mmws + SB * SS * 2;                        // 16 MB
    float*  pl   = (float*)(pacc + KCHUNKS * SB * SH * SS);   // 4 MB

    hipMemsetAsync(d_ws, 0, 512, stream);  // zero Mq2/Mk2 (values >= 0)

    k_ma_qkv<<<SB * (SS / 256), 256, 0, stream>>>(x, Wq, Wk, Wv, qws, kvws, mmws, Mq2, Mk2);
    k_attn<<<SB * SH * KCHUNKS, 256, 0, stream>>>(qws, kvws, Mq2, Mk2, pl, pacc);
    k_epilogue<<<(SB * SS) / 256, 256, 0, stream>>>(x, Wo, bo, pl, pacc, mmws, (float*)d_out);
}

// Round 12
// 89.401 us; speedup vs baseline: 1.0268x; 1.0268x over previous
//
#include <hip/hip_runtime.h>

#define SB 32      // batch
#define SS 2048    // sequence
#define SH 2       // heads
#define SD 4       // head dim
#define SE 8       // embed

#define KCHUNKS 8
#define CHK (SS / KCHUNKS)    // 256 keys per chunk
#define QTILES 2
#define QROWS (SS / QTILES)   // 1024 q rows per block = 256 threads * RROWS
#define RROWS 4               // q rows per thread

#define LOG2E 1.44269504f

typedef float  f32x2 __attribute__((ext_vector_type(2)));
typedef _Float16 f16x2 __attribute__((ext_vector_type(2)));

static __device__ __forceinline__ f32x2 fma2(f32x2 a, f32x2 b, f32x2 c) {
    return __builtin_elementwise_fma(a, b, c);
}

// Raw v_exp_f32 (1 trans instr; libm exp2f adds a denormal-fixup path).
static __device__ __forceinline__ float fast_exp2(float x) {
#if __has_builtin(__builtin_amdgcn_exp2f)
    return __builtin_amdgcn_exp2f(x);
#else
    return exp2f(x);
#endif
}

// v_dot2_f32_f16: a.x*b.x + a.y*b.y + c, f32 accumulation — 1 instr.
static __device__ __forceinline__ float dot2(f16x2 a, f16x2 b, float c) {
#if __has_builtin(__builtin_amdgcn_fdot2)
    return __builtin_amdgcn_fdot2(a, b, c, false);
#else
    return fmaf((float)a.x, (float)b.x, fmaf((float)a.y, (float)b.y, c));
#endif
}

union u32h2 { unsigned u; f16x2 h; };
static __device__ __forceinline__ unsigned packh2(float a, float b) {
    u32h2 c; c.h.x = (_Float16)a; c.h.y = (_Float16)b; return c.u;
}
static __device__ __forceinline__ f16x2 u2h(unsigned u) {
    u32h2 c; c.u = u; return c.h;
}

// ---------------------------------------------------------------------------
// Kernel 1: moving averages + QKV projection. q (pre-scaled by log2e/sqrt(D))
// and k are packed to f16x2 pairs for v_dot2_f32_f16 in the attention kernel;
// v stays f32. Per-(b,h) global max of |q|^2 / |k|^2 (computed on the f32
// values, upper-bounds the f16 dot to ~2^0.03) via LDS reduce + atomicMax.
// ---------------------------------------------------------------------------
__global__ __launch_bounds__(256) void k_ma_qkv(
    const float* __restrict__ x,      // [B,S]
    const float* __restrict__ Wq,     // [4,4] row-major W[e*4+d]
    const float* __restrict__ Wk,
    const float* __restrict__ Wv,
    uint2* __restrict__ qws16,        // [B*H*S] packed f16 {q01,q23}
    uint2* __restrict__ kws16,        // [B*H*S] packed f16 {k01,k23}
    float4* __restrict__ vws,         // [B*H*S]
    float4* __restrict__ mmws,        // [B*S*2]
    float* __restrict__ Mq2,          // [B*H] (zero-initialized)
    float* __restrict__ Mk2)          // [B*H]
{
    __shared__ float xs[272];
    __shared__ float4 red4[256];

    const int tile = blockIdx.x % (SS / 256);
    const int b    = blockIdx.x / (SS / 256);
    const int s0   = tile * 256;
    const float* xrow = x + b * SS;

    for (int i = threadIdx.x; i < 272; i += 256) {
        int idx = s0 - 8 + i;
        idx = min(max(idx, 0), SS - 1);
        xs[i] = xrow[idx];
    }
    __syncthreads();

    const int t = threadIdx.x;
    const int s = s0 + t;

    float mmv[8];
    float c = xs[8 + t];
    #pragma unroll
    for (int h = 1; h <= 8; ++h) {
        c += xs[8 + t - h] + xs[8 + t + h];
        mmv[h - 1] = c * (1.0f / (float)(2 * h + 1));
    }

    mmws[(b * SS + s) * 2 + 0] = make_float4(mmv[0], mmv[1], mmv[2], mmv[3]);
    mmws[(b * SS + s) * 2 + 1] = make_float4(mmv[4], mmv[5], mmv[6], mmv[7]);

    const float qscale = 0.5f * LOG2E;  // 1/sqrt(D) * log2(e)
    float q2h[SH], k2h[SH];
    #pragma unroll
    for (int h = 0; h < SH; ++h) {
        const float t0 = mmv[h * 4 + 0];
        const float t1 = mmv[h * 4 + 1];
        const float t2 = mmv[h * 4 + 2];
        const float t3 = mmv[h * 4 + 3];
        float q[4], k[4], v[4];
        #pragma unroll
        for (int e = 0; e < 4; ++e) {
            q[e] = (t0 * Wq[e * 4 + 0] + t1 * Wq[e * 4 + 1] +
                    t2 * Wq[e * 4 + 2] + t3 * Wq[e * 4 + 3]) * qscale;
            k[e] =  t0 * Wk[e * 4 + 0] + t1 * Wk[e * 4 + 1] +
                    t2 * Wk[e * 4 + 2] + t3 * Wk[e * 4 + 3];
            v[e] =  t0 * Wv[e * 4 + 0] + t1 * Wv[e * 4 + 1] +
                    t2 * Wv[e * 4 + 2] + t3 * Wv[e * 4 + 3];
        }
        const int idx = (b * SH + h) * SS + s;
        qws16[idx] = make_uint2(packh2(q[0], q[1]), packh2(q[2], q[3]));
        kws16[idx] = make_uint2(packh2(k[0], k[1]), packh2(k[2], k[3]));
        vws[idx]   = make_float4(v[0], v[1], v[2], v[3]);
        q2h[h] = q[0]*q[0] + q[1]*q[1] + q[2]*q[2] + q[3]*q[3];
        k2h[h] = k[0]*k[0] + k[1]*k[1] + k[2]*k[2] + k[3]*k[3];
    }

    red4[t] = make_float4(q2h[0], k2h[0], q2h[1], k2h[1]);
    __syncthreads();
    #pragma unroll
    for (int sft = 128; sft > 0; sft >>= 1) {
        if (t < sft) {
            float4 a = red4[t], bb = red4[t + sft];
            red4[t] = make_float4(fmaxf(a.x, bb.x), fmaxf(a.y, bb.y),
                                  fmaxf(a.z, bb.z), fmaxf(a.w, bb.w));
        }
        __syncthreads();
    }
    if (t == 0) {
        const float4 r = red4[0];
        atomicMax((int*)&Mq2[b * SH + 0], __float_as_int(r.x));
        atomicMax((int*)&Mk2[b * SH + 0], __float_as_int(r.y));
        atomicMax((int*)&Mq2[b * SH + 1], __float_as_int(r.z));
        atomicMax((int*)&Mk2[b * SH + 1], __float_as_int(r.w));
    }
}

// ---------------------------------------------------------------------------
// Kernel 2: attention, single pass. Instruction-count-bound (R10 vs R11:
// time invariant to wave count and ILP config -> VALU issue is the limit).
// Per score: 2x v_dot2_f32_f16 (seeded with -m) + 1 v_exp + 1 l-add + 4 PV
// fma = 8 instrs vs 11 before. K (f16x2 pairs, 2 KB) and V (f32, 4 KB) in
// LDS; j wave-uniform -> broadcast reads. Base-2 throughout; raw v_exp_f32.
// Grid = B*H * QTILES * KCHUNKS = 1024 blocks -> 4 blocks/CU.
// ---------------------------------------------------------------------------
__global__ __launch_bounds__(256, 4) void k_attn(
    const uint2* __restrict__ qws16,
    const uint2* __restrict__ kws16,
    const float4* __restrict__ vws,
    const float* __restrict__ Mq2,
    const float* __restrict__ Mk2,
    float* __restrict__ pl,      // [KCHUNKS * B*H*S]  partial sums l
    float4* __restrict__ pacc)   // [KCHUNKS * B*H*S]
{
    __shared__ uint2  Ksh[CHK];   // 2 KB packed f16 keys
    __shared__ float4 Vsh[CHK];   // 4 KB f32 values

    int tmp = blockIdx.x;
    const int kc = tmp % KCHUNKS; tmp /= KCHUNKS;
    const int qt = tmp % QTILES;  tmp /= QTILES;
    const int bh = tmp;

    const int t = threadIdx.x;

    // stage: one key per thread (CHK == 256)
    Ksh[t] = kws16[bh * SS + kc * CHK + t];
    Vsh[t] = vws  [bh * SS + kc * CHK + t];

    const float mq = -sqrtf(Mq2[bh] * Mk2[bh]);   // -m, log2 units

    f16x2 q01[RROWS], q23[RROWS];
    int row[RROWS];
    #pragma unroll
    for (int i = 0; i < RROWS; ++i) {
        row[i] = qt * QROWS + i * 256 + t;   // 4*256 = 1024 = QROWS
        const uint2 qr = qws16[bh * SS + row[i]];
        q01[i] = u2h(qr.x);
        q23[i] = u2h(qr.y);
    }

    float l[RROWS];
    f32x2 acclo[RROWS], acchi[RROWS];
    #pragma unroll
    for (int i = 0; i < RROWS; ++i) {
        l[i] = 0.f;
        acclo[i] = f32x2{0.f, 0.f};
        acchi[i] = f32x2{0.f, 0.f};
    }

    __syncthreads();

    #pragma unroll 4
    for (int j = 0; j < CHK; ++j) {
        const uint2  kk = Ksh[j];       // uniform addr -> broadcast
        const float4 v4 = Vsh[j];
        const f16x2 k01 = u2h(kk.x), k23 = u2h(kk.y);
        const f32x2 vlo = {v4.x, v4.y}, vhi = {v4.z, v4.w};
        #pragma unroll
        for (int i = 0; i < RROWS; ++i) {
            const float d = dot2(q23[i], k23, dot2(q01[i], k01, mq));
            const float p = fast_exp2(d);   // arg = q.k - m  (<= ~0.03)
            l[i] += p;
            const f32x2 pp = {p, p};
            acclo[i] = fma2(pp, vlo, acclo[i]);
            acchi[i] = fma2(pp, vhi, acchi[i]);
        }
    }

    #pragma unroll
    for (int i = 0; i < RROWS; ++i) {
        const int idx = (kc * SB * SH + bh) * SS + row[i];
        pl[idx]   = l[i];
        pacc[idx] = make_float4(acclo[i].x, acclo[i].y, acchi[i].x, acchi[i].y);
    }
}

// ---------------------------------------------------------------------------
// Kernel 3: epilogue. Shift m identical across k-chunks -> plain-sum merge.
// Then o @ Wo^T + bo, channel softmax, trend, seasonal.
// ---------------------------------------------------------------------------
__global__ __launch_bounds__(256) void k_epilogue(
    const float* __restrict__ x,      // [B,S]
    const float* __restrict__ Wo,     // [8,8]
    const float* __restrict__ bo,     // [8]
    const float* __restrict__ pl,
    const float4* __restrict__ pacc,
    const float4* __restrict__ mmws,
    float* __restrict__ out)          // seasonal [B*S] then trend [B*S]
{
    const int pos = blockIdx.x * 256 + threadIdx.x;  // = b*S + s
    const int b = pos / SS;
    const int s = pos % SS;

    float ov[8];
    #pragma unroll
    for (int h = 0; h < SH; ++h) {
        const int bh = b * SH + h;
        float lsum = 0.f, ax = 0.f, ay = 0.f, az = 0.f, aw = 0.f;
        #pragma unroll
        for (int kc = 0; kc < KCHUNKS; ++kc) {
            const int idx = (kc * SB * SH + bh) * SS + s;
            const float4 pa = pacc[idx];
            lsum += pl[idx];
            ax += pa.x; ay += pa.y; az += pa.z; aw += pa.w;
        }
        const float inv = 1.0f / lsum;
        ov[h * 4 + 0] = ax * inv;
        ov[h * 4 + 1] = ay * inv;
        ov[h * 4 + 2] = az * inv;
        ov[h * 4 + 3] = aw * inv;
    }

    float g[8];
    float m = -1e30f;
    #pragma unroll
    for (int e = 0; e < 8; ++e) {
        float acc = bo[e];
        #pragma unroll
        for (int f = 0; f < 8; ++f) acc += ov[f] * Wo[e * 8 + f];
        g[e] = acc;
        m = fmaxf(m, acc);
    }
    float l = 0.0f;
    #pragma unroll
    for (int e = 0; e < 8; ++e) { g[e] = __expf(g[e] - m); l += g[e]; }
    const float inv = 1.0f / l;

    const float4 mm0 = mmws[pos * 2 + 0];
    const float4 mm1 = mmws[pos * 2 + 1];
    const float mv[8] = {mm0.x, mm0.y, mm0.z, mm0.w, mm1.x, mm1.y, mm1.z, mm1.w};

    float trend = 0.0f;
    #pragma unroll
    for (int e = 0; e < 8; ++e) trend += g[e] * inv * mv[e];

    out[pos]           = x[pos] - trend;   // seasonal
    out[SB * SS + pos] = trend;            // trend
}

extern "C" void kernel_launch(void* const* d_in, const int* in_sizes, int n_in,
                              void* d_out, int out_size, void* d_ws, size_t ws_size,
                              hipStream_t stream) {
    const float* x  = (const float*)d_in[0];
    const float* Wq = (const float*)d_in[1];
    const float* Wk = (const float*)d_in[2];
    const float* Wv = (const float*)d_in[3];
    const float* Wo = (const float*)d_in[4];
    const float* bo = (const float*)d_in[5];

    float*  Mq2   = (float*)d_ws;                             // 64 floats
    float*  Mk2   = Mq2 + SB * SH;                            // 64 floats (512 B)
    uint2*  qws16 = (uint2*)((char*)d_ws + 512);              // 1 MB
    uint2*  kws16 = qws16 + SB * SH * SS;                     // 1 MB
    float4* vws   = (float4*)(kws16 + SB * SH * SS);          // 2 MB
    float4* mmws  = vws + SB * SH * SS;                       // 2 MB
    float4* pacc  = mmws + SB * SS * 2;                       // 16 MB
    float*  pl    = (float*)(pacc + KCHUNKS * SB * SH * SS);  // 4 MB

    hipMemsetAsync(d_ws, 0, 512, stream);  // zero Mq2/Mk2 (values >= 0)

    k_ma_qkv<<<SB * (SS / 256), 256, 0, stream>>>(x, Wq, Wk, Wv, qws16, kws16, vws, mmws, Mq2, Mk2);
    k_attn<<<SB * SH * QTILES * KCHUNKS, 256, 0, stream>>>(qws16, kws16, vws, Mq2, Mk2, pl, pacc);
    k_epilogue<<<(SB * SS) / 256, 256, 0, stream>>>(x, Wo, bo, pl, pacc, mmws, (float*)d_out);
}

// Round 13
// 51.167 us; speedup vs baseline: 1.7941x; 1.7472x over previous
//
#include <hip/hip_runtime.h>

#define SB 32      // batch
#define SS 2048    // sequence
#define SH 2       // heads
#define SD 4       // head dim
#define SE 8       // embed

#define LOG2E 1.44269504f

typedef float    f32x16 __attribute__((ext_vector_type(16)));
typedef _Float16 f16x8  __attribute__((ext_vector_type(8)));

// Raw v_exp_f32 (1 trans instr; libm exp2f adds a denormal-fixup path).
static __device__ __forceinline__ float fast_exp2(float x) {
#if __has_builtin(__builtin_amdgcn_exp2f)
    return __builtin_amdgcn_exp2f(x);
#else
    return exp2f(x);
#endif
}

// pack 2 f32 -> 2 f16 (one v_cvt_pkrtz_f16_f32), as raw int
static __device__ __forceinline__ int cvtpk(float a, float b) {
    auto h = __builtin_amdgcn_cvt_pkrtz(a, b);
    union { decltype(h) hh; int i; } u; u.hh = h; return u.i;
}

// exchange register halves across the lane<32 / lane>=32 boundary:
// r0 = [a.lanes0-31 | b.lanes0-31], r1 = [a.lanes32-63 | b.lanes32-63]
static __device__ __forceinline__ void swap32(int a, int b, int lane, int& r0, int& r1) {
#if __has_builtin(__builtin_amdgcn_permlane32_swap)
    auto r = __builtin_amdgcn_permlane32_swap(a, b, false, false);
    r0 = r[0]; r1 = r[1];
#else
    const int blo = __builtin_amdgcn_ds_bpermute((lane & 31) << 2, b);        // b[lane&31]
    const int ahi = __builtin_amdgcn_ds_bpermute(((lane ^ 32) & 63) << 2, a); // a[lane^32]
    r0 = (lane < 32) ? a : blo;
    r1 = (lane < 32) ? ahi : b;
#endif
}

static __device__ __forceinline__ f16x8 frag2(unsigned x, unsigned y) {
    union { unsigned u[4]; f16x8 h; } c;
    c.u[0] = x; c.u[1] = y; c.u[2] = 0; c.u[3] = 0; return c.h;
}
static __device__ __forceinline__ f16x8 frag4(uint4 v) {
    union { uint4 u; f16x8 h; } c; c.u = v; return c.h;
}
static __device__ __forceinline__ f16x8 fragi(int a, int b, int c_, int d) {
    union { int u[4]; f16x8 h; } c;
    c.u[0] = a; c.u[1] = b; c.u[2] = c_; c.u[3] = d; return c.h;
}

union u32h2 { unsigned u; _Float16 h[2]; };
static __device__ __forceinline__ unsigned packh2(float a, float b) {
    u32h2 c; c.h[0] = (_Float16)a; c.h[1] = (_Float16)b; return c.u;
}

// ---------------------------------------------------------------------------
// Kernel 1: moving averages + QKV projection. q (pre-scaled by log2e/sqrt(D))
// and k packed to f16 (uint2/row); V written TRANSPOSED as f16 rows
// VTg[bh][c=0..3][s] for the PV mfma A-operand. No shift bound needed:
// softmax shift cancels exactly (uniform per b,h), and raw scores are small
// enough (|score| <= ~40 log2 units) that exp2 stays in f32 range.
// ---------------------------------------------------------------------------
__global__ __launch_bounds__(256) void k_ma_qkv(
    const float* __restrict__ x,      // [B,S]
    const float* __restrict__ Wq,     // [4,4] row-major W[e*4+d]
    const float* __restrict__ Wk,
    const float* __restrict__ Wv,
    uint2* __restrict__ qws16,        // [B*H*S] packed f16 {q01,q23}
    uint2* __restrict__ kws16,        // [B*H*S]
    _Float16* __restrict__ vtg,       // [B*H][4][S] V transposed, f16
    float4* __restrict__ mmws)        // [B*S*2]
{
    __shared__ float xs[272];

    const int tile = blockIdx.x % (SS / 256);
    const int b    = blockIdx.x / (SS / 256);
    const int s0   = tile * 256;
    const float* xrow = x + b * SS;

    for (int i = threadIdx.x; i < 272; i += 256) {
        int idx = s0 - 8 + i;
        idx = min(max(idx, 0), SS - 1);
        xs[i] = xrow[idx];
    }
    __syncthreads();

    const int t = threadIdx.x;
    const int s = s0 + t;

    float mmv[8];
    float c = xs[8 + t];
    #pragma unroll
    for (int h = 1; h <= 8; ++h) {
        c += xs[8 + t - h] + xs[8 + t + h];
        mmv[h - 1] = c * (1.0f / (float)(2 * h + 1));
    }

    mmws[(b * SS + s) * 2 + 0] = make_float4(mmv[0], mmv[1], mmv[2], mmv[3]);
    mmws[(b * SS + s) * 2 + 1] = make_float4(mmv[4], mmv[5], mmv[6], mmv[7]);

    const float qscale = 0.5f * LOG2E;  // 1/sqrt(D) * log2(e)
    #pragma unroll
    for (int h = 0; h < SH; ++h) {
        const float t0 = mmv[h * 4 + 0];
        const float t1 = mmv[h * 4 + 1];
        const float t2 = mmv[h * 4 + 2];
        const float t3 = mmv[h * 4 + 3];
        float q[4], k[4], v[4];
        #pragma unroll
        for (int e = 0; e < 4; ++e) {
            q[e] = (t0 * Wq[e * 4 + 0] + t1 * Wq[e * 4 + 1] +
                    t2 * Wq[e * 4 + 2] + t3 * Wq[e * 4 + 3]) * qscale;
            k[e] =  t0 * Wk[e * 4 + 0] + t1 * Wk[e * 4 + 1] +
                    t2 * Wk[e * 4 + 2] + t3 * Wk[e * 4 + 3];
            v[e] =  t0 * Wv[e * 4 + 0] + t1 * Wv[e * 4 + 1] +
                    t2 * Wv[e * 4 + 2] + t3 * Wv[e * 4 + 3];
        }
        const int bh  = b * SH + h;
        const int idx = bh * SS + s;
        qws16[idx] = make_uint2(packh2(q[0], q[1]), packh2(q[2], q[3]));
        kws16[idx] = make_uint2(packh2(k[0], k[1]), packh2(k[2], k[3]));
        #pragma unroll
        for (int e = 0; e < 4; ++e)
            vtg[(bh * 4 + e) * SS + s] = (_Float16)v[e];
    }
}

// ---------------------------------------------------------------------------
// Kernel 2: MFMA flash attention. Per wave: one 32-row q-block, loop over all
// 64 j-tiles (32 keys each).
//   S^T tile  = mfma_32x32x16_f16(A=K-tile[32j x 16dpad], B=Q[16dpad x 32i])
//   P~ = exp2(S^T)  (16 v_exp; no shift — cancels in the final division)
//   PV: O^T[c,i] += mfma(A=V^T[32cpad x 16j], B=P~^T-frag)  (x2 halves)
// V^T is staged in LDS with a ones-row at c=4, so row 4 of O^T accumulates
// l = sum(P~) for free. B-frags for PV built from S^T's C-layout with
// cvt_pkrtz pairs + permlane32_swap half-exchanges (HK T12 pattern).
// Layout facts (guide, HW-verified): C/D col=lane&31, row=(reg&3)+8*(reg>>2)
// +4*(lane>>5); A/B row|col=lane&31, k=8*(lane>>5)+elem.
// Grid = B*H * 16 blocks, 4 waves/block -> 64 i-blocks per (b,h).
// ---------------------------------------------------------------------------
#define LDS_K    0
#define LDS_VT   16384
#define VT_STRIDE 4112          // (2048+8) f16 -> breaks bank alignment
#define LDS_Z    36944          // 128 B zero slot (padded-lane reads)
#define LDS_SIZE 37376

__global__ __launch_bounds__(256) void k_attn(
    const uint2* __restrict__ qws16,
    const uint2* __restrict__ kws16,
    const unsigned* __restrict__ vtg,   // u32 view of VT f16 [bh][4][SS]
    float4* __restrict__ ows)           // [B*H*S] normalized attention out
{
    __shared__ __align__(16) char lds[LDS_SIZE];

    const int t      = threadIdx.x;
    const int bh     = blockIdx.x >> 4;
    const int w      = t >> 6;
    const int iblock = (blockIdx.x & 15) * 4 + w;
    const int lane   = t & 63;
    const int c31    = lane & 31;

    // ---- stage K (16 KB: uint2 per key) ----
    const uint2* kg = kws16 + bh * SS;
    for (int i = t; i < SS; i += 256)
        *(uint2*)(lds + LDS_K + i * 8) = kg[i];
    // ---- stage V^T rows 0..3 (f16, padded row stride) ----
    const unsigned* vg = vtg + bh * 4 * (SS / 2);
    for (int i = t; i < 4 * (SS / 2); i += 256) {
        const int cc = i >> 10, col = i & 1023;
        *(unsigned*)(lds + LDS_VT + cc * VT_STRIDE + col * 4) = vg[i];
    }
    // ---- ones row (c = 4) for the l-accumulator ----
    for (int i = t; i < SS / 2; i += 256)
        *(unsigned*)(lds + LDS_VT + 4 * VT_STRIDE + i * 4) = 0x3C003C00u;
    // ---- zero slot ----
    if (t < 32) *(unsigned*)(lds + LDS_Z + t * 4) = 0u;
    __syncthreads();

    // Q B-frag (fixed per wave): lane holds col i=lane&31, k=d (lanes>=32 pad 0)
    uint2 qq = qws16[bh * SS + iblock * 32 + c31];
    if (lane >= 32) { qq.x = 0u; qq.y = 0u; }
    const f16x8 bq = frag2(qq.x, qq.y);

    // per-lane LDS addresses (padded lanes read the zero slot, never step)
    int kaddr = (lane < 32) ? (LDS_K + lane * 8) : LDS_Z;
    const int kstep = (lane < 32) ? 256 : 0;            // 32 keys * 8 B
    int vaddr = (c31 < 5) ? (LDS_VT + c31 * VT_STRIDE + (lane >> 5) * 16) : LDS_Z;
    const int vstep = (c31 < 5) ? 64 : 0;               // 32 j * 2 B

    f32x16 oacc = {0,0,0,0,0,0,0,0,0,0,0,0,0,0,0,0};
    const f32x16 zc = {0,0,0,0,0,0,0,0,0,0,0,0,0,0,0,0};

    // preload tile 0
    uint2 kk  = *(const uint2*)(lds + kaddr); kaddr += kstep;
    uint4 vv0 = *(const uint4*)(lds + vaddr);
    uint4 vv1 = *(const uint4*)(lds + vaddr + 32); vaddr += vstep;

    for (int jt = 0; jt < SS / 32; ++jt) {
        const f16x8 ak  = frag2(kk.x, kk.y);
        const f16x8 av0 = frag4(vv0);
        const f16x8 av1 = frag4(vv1);

        f32x16 d = __builtin_amdgcn_mfma_f32_32x32x16_f16(ak, bq, zc, 0, 0, 0);

        // preload next tile (last iter overruns into in-bounds pad; unused)
        kk  = *(const uint2*)(lds + kaddr); kaddr += kstep;
        vv0 = *(const uint4*)(lds + vaddr);
        vv1 = *(const uint4*)(lds + vaddr + 32); vaddr += vstep;

        float p[16];
        #pragma unroll
        for (int r = 0; r < 16; ++r) p[r] = fast_exp2(d[r]);

        const int pk01 = cvtpk(p[0],  p[1]),  pk23 = cvtpk(p[2],  p[3]);
        const int pk45 = cvtpk(p[4],  p[5]),  pk67 = cvtpk(p[6],  p[7]);
        const int pk89 = cvtpk(p[8],  p[9]),  pkAB = cvtpk(p[10], p[11]);
        const int pkCD = cvtpk(p[12], p[13]), pkEF = cvtpk(p[14], p[15]);

        int B0, B1, B2, B3, C0, C1, C2, C3;
        swap32(pk01, pk45, lane, B0, B2);   // j {0,1}|{8,9}   and {4,5}|{12,13}
        swap32(pk23, pk67, lane, B1, B3);   // j {2,3}|{10,11} and {6,7}|{14,15}
        swap32(pk89, pkCD, lane, C0, C2);   // j {16,17}|{24,25} and {20,21}|{28,29}
        swap32(pkAB, pkEF, lane, C1, C3);   // j {18,19}|{26,27} and {22,23}|{30,31}

        const f16x8 bp0 = fragi(B0, B1, B2, B3);   // P~^T B-frag, j 0..15
        const f16x8 bp1 = fragi(C0, C1, C2, C3);   // P~^T B-frag, j 16..31

        oacc = __builtin_amdgcn_mfma_f32_32x32x16_f16(av0, bp0, oacc, 0, 0, 0);
        oacc = __builtin_amdgcn_mfma_f32_32x32x16_f16(av1, bp1, oacc, 0, 0, 0);
    }

    // l sits in reg0 of lanes>=32 (row c=4); bring to lanes<32 and normalize.
    union { float f; int i; } u0; u0.f = oacc[0];
    int s0i, s1i;
    swap32(u0.i, u0.i, lane, s0i, s1i);
    union { int i; float f; } ul; ul.i = s1i;      // lanes<32: l from lane+32
    if (lane < 32) {
        const float inv = 1.0f / ul.f;
        ows[bh * SS + iblock * 32 + lane] =
            make_float4(oacc[0] * inv, oacc[1] * inv, oacc[2] * inv, oacc[3] * inv);
    }
}

// ---------------------------------------------------------------------------
// Kernel 3: epilogue. O already normalized. o @ Wo^T + bo, channel softmax,
// trend, seasonal.
// ---------------------------------------------------------------------------
__global__ __launch_bounds__(256) void k_epilogue(
    const float* __restrict__ x,      // [B,S]
    const float* __restrict__ Wo,     // [8,8]
    const float* __restrict__ bo,     // [8]
    const float4* __restrict__ ows,
    const float4* __restrict__ mmws,
    float* __restrict__ out)          // seasonal [B*S] then trend [B*S]
{
    const int pos = blockIdx.x * 256 + threadIdx.x;  // = b*S + s
    const int b = pos / SS;
    const int s = pos % SS;

    const float4 o0 = ows[(b * SH + 0) * SS + s];
    const float4 o1 = ows[(b * SH + 1) * SS + s];
    const float ov[8] = {o0.x, o0.y, o0.z, o0.w, o1.x, o1.y, o1.z, o1.w};

    float g[8];
    float m = -1e30f;
    #pragma unroll
    for (int e = 0; e < 8; ++e) {
        float acc = bo[e];
        #pragma unroll
        for (int f = 0; f < 8; ++f) acc += ov[f] * Wo[e * 8 + f];
        g[e] = acc;
        m = fmaxf(m, acc);
    }
    float l = 0.0f;
    #pragma unroll
    for (int e = 0; e < 8; ++e) { g[e] = __expf(g[e] - m); l += g[e]; }
    const float inv = 1.0f / l;

    const float4 mm0 = mmws[pos * 2 + 0];
    const float4 mm1 = mmws[pos * 2 + 1];
    const float mv[8] = {mm0.x, mm0.y, mm0.z, mm0.w, mm1.x, mm1.y, mm1.z, mm1.w};

    float trend = 0.0f;
    #pragma unroll
    for (int e = 0; e < 8; ++e) trend += g[e] * inv * mv[e];

    out[pos]           = x[pos] - trend;   // seasonal
    out[SB * SS + pos] = trend;            // trend
}

extern "C" void kernel_launch(void* const* d_in, const int* in_sizes, int n_in,
                              void* d_out, int out_size, void* d_ws, size_t ws_size,
                              hipStream_t stream) {
    const float* x  = (const float*)d_in[0];
    const float* Wq = (const float*)d_in[1];
    const float* Wk = (const float*)d_in[2];
    const float* Wv = (const float*)d_in[3];
    const float* Wo = (const float*)d_in[4];
    const float* bo = (const float*)d_in[5];

    uint2*     qws16 = (uint2*)d_ws;                        // 1 MB
    uint2*     kws16 = qws16 + SB * SH * SS;                // 1 MB
    _Float16*  vtg   = (_Float16*)(kws16 + SB * SH * SS);   // 1 MB  [bh][4][S]
    float4*    mmws  = (float4*)(vtg + SB * SH * 4 * SS);   // 2 MB
    float4*    ows   = mmws + SB * SS * 2;                  // 2 MB

    k_ma_qkv<<<SB * (SS / 256), 256, 0, stream>>>(x, Wq, Wk, Wv, qws16, kws16, vtg, mmws);
    k_attn<<<SB * SH * 16, 256, 0, stream>>>(qws16, kws16, (const unsigned*)vtg, ows);
    k_epilogue<<<(SB * SS) / 256, 256, 0, stream>>>(x, Wo, bo, ows, mmws, (float*)d_out);
}